// Round 13
// baseline (1057.546 us; speedup 1.0000x reference)
//
#include <hip/hip_runtime.h>
#include <math.h>

#define BB 8
#define NN 2048
#define PP 64
#define KK 32
#define DD 384
#define DEPTH 12
#define DI 768
#define DS 16
#define DCONV 4
#define DTR 24
#define NC 40
#define LL 128  // 2*PP
#define XROW (DTR + 2 * DS)  // 56
#define NR (BB * LL)         // 1024

using bf16x8 = __attribute__((ext_vector_type(8))) short;
using floatx4 = __attribute__((ext_vector_type(4))) float;

// ---------------------------------------------------------------- helpers
__device__ __forceinline__ float gelu_exact(float x) {
    return 0.5f * x * (1.0f + erff(x * 0.70710678118654752440f));
}
__device__ __forceinline__ float siluf(float x) {
    return x / (1.0f + expf(-x));
}
__device__ __forceinline__ unsigned short f2bf(float f) {
    unsigned u = __float_as_uint(f);
    u += 0x7fffu + ((u >> 16) & 1u);   // round-to-nearest-even
    return (unsigned short)(u >> 16);
}
__device__ __forceinline__ float bf2f(short s) {
    return __uint_as_float(((unsigned)(unsigned short)s) << 16);
}
__device__ __forceinline__ unsigned spread_bits(unsigned v) {
    v &= 1023u;
    v = (v | (v << 16)) & 50331903u;
    v = (v | (v << 8)) & 50393103u;
    v = (v | (v << 4)) & 51130563u;
    v = (v | (v << 2)) & 153391689u;
    return v;
}

// ---------------------------------------------------------------- one-shot weight conversions (all four)
__global__ void k_cvt(const float* __restrict__ in_w, const float* __restrict__ out_w,
                      const float* __restrict__ pe_w3, const float* __restrict__ xp,
                      unsigned short* __restrict__ inwbf, unsigned short* __restrict__ owbf,
                      unsigned short* __restrict__ w3bf, unsigned short* __restrict__ xpbf)
{
    int idx = blockIdx.x * 256 + threadIdx.x;
    const int n1 = DEPTH * 2 * DI * DD;
    const int n2 = DEPTH * DD * DI;
    const int n3 = DD * 128;
    const int n4 = DEPTH * 64 * DI;
    if (idx < n1) { inwbf[idx] = f2bf(in_w[idx]); return; }
    idx -= n1;
    if (idx < n2) { owbf[idx] = f2bf(out_w[idx]); return; }
    idx -= n2;
    if (idx < n3) { w3bf[idx] = f2bf(pe_w3[idx]); return; }
    idx -= n3;
    if (idx < n4) {
        int i = idx / (64 * DI);
        int rem = idx - i * 64 * DI;
        int n = rem / DI, k = rem % DI;
        float v = (n < XROW) ? xp[(size_t)i * XROW * DI + (size_t)n * DI + k] : 0.f;
        xpbf[idx] = f2bf(v);
    }
}

// ---------------------------------------------------------------- KNN: one block per (b,p)
__global__ __launch_bounds__(256) void k_knn(const float* __restrict__ data,
                                             int* __restrict__ knn_out,
                                             float* __restrict__ centers)
{
    const int bp = blockIdx.x;
    const int b = bp >> 6, p = bp & 63;
    const int tid = threadIdx.x;
    const int lane = tid & 63, wid = tid >> 6;
    const float* X = data + (size_t)b * NN * 3;

    const float cx = X[p * 32 * 3 + 0];
    const float cy = X[p * 32 * 3 + 1];
    const float cz = X[p * 32 * 3 + 2];
    if (tid == 0) {
        centers[(b * PP + p) * 3 + 0] = cx;
        centers[(b * PP + p) * 3 + 1] = cy;
        centers[(b * PP + p) * 3 + 2] = cz;
    }

    unsigned long long pk[8];
#pragma unroll
    for (int q = 0; q < 8; q++) {
        int i = tid + 256 * q;
        float dx = cx - X[i * 3 + 0];
        float dy = cy - X[i * 3 + 1];
        float dz = cz - X[i * 3 + 2];
        float d2 = dx * dx + dy * dy + dz * dz;
        pk[q] = ((unsigned long long)__float_as_uint(d2) << 32) | (unsigned)i;
    }

    __shared__ unsigned long long wred[4];
    __shared__ int klist[KK];
    for (int k = 0; k < KK; k++) {
        unsigned long long m = pk[0];
#pragma unroll
        for (int q = 1; q < 8; q++) m = pk[q] < m ? pk[q] : m;
#pragma unroll
        for (int off = 32; off; off >>= 1) {
            unsigned long long o = __shfl_xor(m, off);
            m = o < m ? o : m;
        }
        if (lane == 0) wred[wid] = m;
        __syncthreads();
        unsigned long long g = wred[0];
#pragma unroll
        for (int w = 1; w < 4; w++) g = wred[w] < g ? wred[w] : g;
#pragma unroll
        for (int q = 0; q < 8; q++)
            if (pk[q] == g) pk[q] = ~0ull;
        if (tid == 0) klist[k] = (int)(g & 0xffffffffu);
        __syncthreads();
    }
    if (tid < KK) knn_out[bp * KK + tid] = klist[tid];
}

// ---------------------------------------------------------------- patch-embed MLP: one block per (b,p)
__global__ __launch_bounds__(256) void k_pe_mlp(
    const float* __restrict__ data, const int* __restrict__ knn_in,
    const float* __restrict__ w1, const float* __restrict__ b1,
    const float* __restrict__ g1, const float* __restrict__ be1,
    const float* __restrict__ w2, const float* __restrict__ b2,
    const float* __restrict__ g2, const float* __restrict__ be2,
    const unsigned short* __restrict__ w3bf, const float* __restrict__ b3,
    const float* __restrict__ g3, const float* __restrict__ be3,
    float* __restrict__ tokens)
{
    const int bp = blockIdx.x;
    const int b = bp >> 6, p = bp & 63;
    const int tid = threadIdx.x;
    const float* X = data + (size_t)b * NN * 3;
    const float inv_den = 0.99999500003749968752f; // 1/sqrt(1+1e-5)

    __shared__ float nxs[KK * 3];
    __shared__ float h1s[KK * 64];
    __shared__ short h2b[KK * 136];

    const float cx = X[p * 32 * 3 + 0];
    const float cy = X[p * 32 * 3 + 1];
    const float cz = X[p * 32 * 3 + 2];
    if (tid < KK) {
        int q = knn_in[bp * KK + tid];
        nxs[tid * 3 + 0] = X[q * 3 + 0] - cx;
        nxs[tid * 3 + 1] = X[q * 3 + 1] - cy;
        nxs[tid * 3 + 2] = X[q * 3 + 2] - cz;
    }
    __syncthreads();

    for (int e = tid; e < KK * 64; e += 256) {
        int j = e >> 6, c = e & 63;
        float v = nxs[j * 3 + 0] * w1[c * 3 + 0] + nxs[j * 3 + 1] * w1[c * 3 + 1] +
                  nxs[j * 3 + 2] * w1[c * 3 + 2] + b1[c];
        v = v * (g1[c] * inv_den) + be1[c];
        h1s[j * 64 + c] = gelu_exact(v);
    }
    __syncthreads();

    for (int e = tid; e < KK * 128; e += 256) {
        int j = e >> 7, c = e & 127;
        const float4* wr = (const float4*)(w2 + (size_t)c * 64);
        const float4* hr = (const float4*)(h1s + j * 64);
        float acc = 0.f;
#pragma unroll
        for (int q = 0; q < 16; q++) {
            float4 wv = wr[q], hv = hr[q];
            acc += hv.x * wv.x + hv.y * wv.y + hv.z * wv.z + hv.w * wv.w;
        }
        float v = (acc + b2[c]) * (g2[c] * inv_den) + be2[c];
        h2b[j * 136 + c] = (short)f2bf(gelu_exact(v));
    }
    __syncthreads();

    const int wave = tid >> 6, lane = tid & 63;
    const int quad = lane >> 4, r = lane & 15;
    floatx4 acc3[2][6] = {};
#pragma unroll
    for (int ks = 0; ks < 4; ks++) {
        const int k0 = ks * 32;
        bf16x8 af[2];
        af[0] = *(const bf16x8*)(h2b + (size_t)r * 136 + quad * 8 + k0);
        af[1] = *(const bf16x8*)(h2b + (size_t)(16 + r) * 136 + quad * 8 + k0);
        bf16x8 bfv[6];
#pragma unroll
        for (int nj = 0; nj < 6; nj++) {
            int n = wave * 96 + nj * 16 + r;
            bfv[nj] = *(const bf16x8*)(w3bf + (size_t)n * 128 + quad * 8 + k0);
        }
#pragma unroll
        for (int mi = 0; mi < 2; mi++)
#pragma unroll
            for (int nj = 0; nj < 6; nj++)
                acc3[mi][nj] = __builtin_amdgcn_mfma_f32_16x16x32_bf16(af[mi], bfv[nj], acc3[mi][nj], 0, 0, 0);
    }
#pragma unroll
    for (int nj = 0; nj < 6; nj++) {
        int col = wave * 96 + nj * 16 + r;
        float sc = g3[col] * inv_den;
        float offc = b3[col] * sc + be3[col];
        float m = -3.4e38f;
#pragma unroll
        for (int mi = 0; mi < 2; mi++)
#pragma unroll
            for (int r2 = 0; r2 < 4; r2++)
                m = fmaxf(m, acc3[mi][nj][r2] * sc + offc);
        m = fmaxf(m, __shfl_xor(m, 16));
        m = fmaxf(m, __shfl_xor(m, 32));
        if (quad == 0) tokens[(size_t)bp * DD + col] = m;
    }
}

// ---------------------------------------------------------------- build token sequence + fused SFC ordering
// grid (16, BB): x = 8-row chunk, y = batch.  Each block redundantly computes its
// batch's z-order ranks in LDS (64 keys, trivial), then builds 8 rows of t.
__global__ __launch_bounds__(256) void k_build_t(
    const float* __restrict__ tokens, const float* __restrict__ centers,
    const float* __restrict__ hs, const float* __restrict__ hb,
    const float* __restrict__ ts, const float* __restrict__ tb,
    const float* __restrict__ pos, float* __restrict__ t)
{
    const int b = blockIdx.y, chunk = blockIdx.x;
    const int tid = threadIdx.x;

    __shared__ float csh[PP][3];
    __shared__ float slo[3], shi[3];
    __shared__ unsigned khs[PP], kts[PP];
    __shared__ int ordh[PP], ordth[PP];

    if (tid < PP) {
        csh[tid][0] = centers[(b * PP + tid) * 3 + 0];
        csh[tid][1] = centers[(b * PP + tid) * 3 + 1];
        csh[tid][2] = centers[(b * PP + tid) * 3 + 2];
    }
    __syncthreads();
    if (tid == 0) {
        for (int k = 0; k < 3; k++) {
            float lo = csh[0][k], hi = csh[0][k];
            for (int j = 1; j < PP; j++) { lo = fminf(lo, csh[j][k]); hi = fmaxf(hi, csh[j][k]); }
            slo[k] = lo; shi[k] = hi;
        }
    }
    __syncthreads();
    if (tid < PP) {
        int q[3];
        for (int k = 0; k < 3; k++) {
            float v = (csh[tid][k] - slo[k]) / (shi[k] - slo[k] + 1e-6f) * 1023.0f;
            int qi = (int)v;
            qi = qi < 0 ? 0 : (qi > 1023 ? 1023 : qi);
            q[k] = qi;
        }
        khs[tid] = spread_bits((unsigned)q[0]) | (spread_bits((unsigned)q[1]) << 1) |
                   (spread_bits((unsigned)q[2]) << 2);
        kts[tid] = spread_bits((unsigned)q[2]) | (spread_bits((unsigned)q[1]) << 1) |
                   (spread_bits((unsigned)q[0]) << 2);
    }
    __syncthreads();
    if (tid < PP) {
        unsigned kh = khs[tid], kt = kts[tid];
        int rh = 0, rt = 0;
        for (int j = 0; j < PP; j++) {
            unsigned a = khs[j];
            rh += (a < kh) || (a == kh && j < tid);
            unsigned c = kts[j];
            rt += (c < kt) || (c == kt && j < tid);
        }
        ordh[rh] = tid;
        ordth[rt] = tid;
    }
    __syncthreads();

    for (int e = tid; e < 8 * DD; e += 256) {
        const int l = chunk * 8 + (e / DD);
        const int d = e % DD;
        float v;
        if (l < PP) {
            int src = ordh[l];
            v = tokens[((size_t)b * PP + src) * DD + d] * hs[d] + hb[d] + pos[l * DD + d];
        } else {
            int l2 = l - PP;
            int src = ordth[l2];
            v = tokens[((size_t)b * PP + src) * DD + d] * ts[d] + tb[d] + pos[l2 * DD + d];
        }
        t[((size_t)b * LL + l) * DD + d] = v;
    }
}

// ---------------------------------------------------------------- LN: t -> tbf (bf16), one wave per row; zero xdbl
__global__ __launch_bounds__(256) void k_stats(const float* __restrict__ t,
                                               const float* __restrict__ g,
                                               const float* __restrict__ gb,
                                               unsigned short* __restrict__ tbf,
                                               float* __restrict__ xdbl)
{
    const int tid = threadIdx.x;
    // zero this block's xdbl chunk (NR*XROW = 57344 = 256 blocks * 224)
    {
        int zi = blockIdx.x * 224 + tid;
        if (tid < 224) xdbl[zi] = 0.f;
    }
    const int wid = tid >> 6, lane = tid & 63;
    const int row = blockIdx.x * 4 + wid;
    const size_t base = (size_t)row * DD;
    float v[6];
    float s = 0.f, q = 0.f;
#pragma unroll
    for (int j = 0; j < 6; j++) {
        v[j] = t[base + lane + 64 * j];
        s += v[j]; q += v[j] * v[j];
    }
#pragma unroll
    for (int off = 32; off; off >>= 1) { s += __shfl_xor(s, off); q += __shfl_xor(q, off); }
    float mean = s * (1.0f / DD);
    float var = q * (1.0f / DD) - mean * mean;
    float inv = 1.0f / sqrtf(var + 1e-5f);
#pragma unroll
    for (int j = 0; j < 6; j++) {
        int i = lane + 64 * j;
        tbf[base + i] = f2bf((v[j] - mean) * inv * g[i] + gb[i]);
    }
}

// ---------------------------------------------------------------- xz MFMA GEMM (128 tokens x 64 cols) + fused conv/SiLU
// + fused xdbl partial (atomicAdd into xdbl; xdbl pre-zeroed by k_stats).
// grid (24, 8): x = 64-col tile (12 xc + 12 z), y = batch.
__global__ __launch_bounds__(256) void k_mfma_xz(
    const unsigned short* __restrict__ tbf,
    const unsigned short* __restrict__ inwbf,
    const float* __restrict__ cw, const float* __restrict__ cb,
    const unsigned short* __restrict__ xpbf,
    unsigned short* __restrict__ xcbf, unsigned short* __restrict__ zsbf,
    float* __restrict__ xdbl)
{
    __shared__ short ct[128][72];   // 64 cols + 8 pad
    const int tid = threadIdx.x;
    const int wave = tid >> 6, lane = tid & 63;
    const int quad = lane >> 4, r = lane & 15;
    const int wm = wave >> 1, wn = wave & 1;
    const int b = blockIdx.y;
    const int n0 = blockIdx.x * 64;
    const int m0 = b * 128 + wm * 64;

    floatx4 acc[4][2] = {};
    const unsigned short* Ab = tbf + (size_t)(m0 + r) * DD + quad * 8;
    const unsigned short* Bb = inwbf + (size_t)(n0 + wn * 32 + r) * DD + quad * 8;
    for (int k0 = 0; k0 < DD; k0 += 32) {
        bf16x8 af[4], bfv[2];
#pragma unroll
        for (int i = 0; i < 4; i++)
            af[i] = *(const bf16x8*)(Ab + (size_t)(i * 16) * DD + k0);
#pragma unroll
        for (int j = 0; j < 2; j++)
            bfv[j] = *(const bf16x8*)(Bb + (size_t)(j * 16) * DD + k0);
#pragma unroll
        for (int i = 0; i < 4; i++)
#pragma unroll
            for (int j = 0; j < 2; j++)
                acc[i][j] = __builtin_amdgcn_mfma_f32_16x16x32_bf16(af[i], bfv[j], acc[i][j], 0, 0, 0);
    }

    // C -> LDS (bf16).  row = wm*64 + i*16 + quad*4 + r2, col = wn*32 + j*16 + r
#pragma unroll
    for (int i = 0; i < 4; i++)
#pragma unroll
        for (int r2 = 0; r2 < 4; r2++) {
            short* cp = &ct[wm * 64 + i * 16 + quad * 4 + r2][wn * 32 + r];
#pragma unroll
            for (int j = 0; j < 2; j++)
                cp[j * 16] = (short)f2bf(acc[i][j][r2]);
        }
    __syncthreads();

    const int l0 = (tid >> 3) * 4;      // 4 rows per thread
    const int c0 = (tid & 7) * 8;       // 8 cols per thread
    if (n0 < DI) {
        float cwv[8][4], cbv[8];
#pragma unroll
        for (int q = 0; q < 8; q++) {
            *(float4*)cwv[q] = *(const float4*)(cw + (size_t)(n0 + c0 + q) * 4);
            cbv[q] = cb[n0 + c0 + q];
        }
        unsigned short ov[4][8];
#pragma unroll
        for (int dl = 0; dl < 4; dl++) {
            const int l = l0 + dl;
            float u[8];
#pragma unroll
            for (int q = 0; q < 8; q++) u[q] = cbv[q];
#pragma unroll
            for (int j = 0; j < DCONV; j++) {
                int lt = l - (DCONV - 1) + j;
                if (lt >= 0) {
                    bf16x8 x = *(const bf16x8*)&ct[lt][c0];
#pragma unroll
                    for (int q = 0; q < 8; q++) u[q] += bf2f(x[q]) * cwv[q][j];
                }
            }
#pragma unroll
            for (int q = 0; q < 8; q++) ov[dl][q] = f2bf(siluf(u[q]));
        }
        __syncthreads();   // all pre-conv reads done
#pragma unroll
        for (int dl = 0; dl < 4; dl++) {
            const int l = l0 + dl;
            *(bf16x8*)&ct[l][c0] = *(bf16x8*)ov[dl];
            *(bf16x8*)(xcbf + (size_t)(b * LL + l) * DI + n0 + c0) = *(bf16x8*)ov[dl];
        }
        __syncthreads();

        // fused xdbl partial: K = 64 (this block's channel slice), 4 waves x 32 rows,
        // accumulated into xdbl via atomics (12 contributions per element).
        floatx4 acc2[2][4] = {};
#pragma unroll
        for (int k0 = 0; k0 < 64; k0 += 32) {
            bf16x8 af2[2], bfv2[4];
#pragma unroll
            for (int i = 0; i < 2; i++)
                af2[i] = *(const bf16x8*)&ct[wave * 32 + i * 16 + r][k0 + quad * 8];
#pragma unroll
            for (int nj = 0; nj < 4; nj++)
                bfv2[nj] = *(const bf16x8*)(xpbf + (size_t)(nj * 16 + r) * DI + n0 + k0 + quad * 8);
#pragma unroll
            for (int i = 0; i < 2; i++)
#pragma unroll
                for (int nj = 0; nj < 4; nj++)
                    acc2[i][nj] = __builtin_amdgcn_mfma_f32_16x16x32_bf16(af2[i], bfv2[nj], acc2[i][nj], 0, 0, 0);
        }
#pragma unroll
        for (int i = 0; i < 2; i++)
#pragma unroll
            for (int nj = 0; nj < 4; nj++) {
                int col = nj * 16 + r;
                if (col < XROW) {
#pragma unroll
                    for (int r2 = 0; r2 < 4; r2++) {
                        int row = b * LL + wave * 32 + i * 16 + quad * 4 + r2;
                        atomicAdd(&xdbl[(size_t)row * XROW + col], acc2[i][nj][r2]);
                    }
                }
            }
    } else {
        const int nz = n0 - DI;
#pragma unroll
        for (int dl = 0; dl < 4; dl++) {
            const int l = l0 + dl;
            bf16x8 x = *(const bf16x8*)&ct[l][c0];
            unsigned short o[8];
#pragma unroll
            for (int q = 0; q < 8; q++) o[q] = f2bf(siluf(bf2f(x[q])));
            *(bf16x8*)(zsbf + (size_t)(b * LL + l) * DI + nz + c0) = *(bf16x8*)o;
        }
    }
}

// ---------------------------------------------------------------- chunk-parallel selective scan (1 channel / 128-thr block)
__global__ __launch_bounds__(128) void k_scan(
    const float* __restrict__ xdbl,
    const unsigned short* __restrict__ xcbf, const unsigned short* __restrict__ zsbf,
    const float* __restrict__ dtw, const float* __restrict__ dtb,
    const float* __restrict__ Alog, const float* __restrict__ Dp,
    unsigned short* __restrict__ ybf)
{
    const int tid = threadIdx.x;
    const int b = blockIdx.x / DI;
    const int d = blockIdx.x % DI;

    __shared__ float da[LL][17];
    __shared__ float Bsh[LL][17];
    __shared__ float Csh[LL][17];
    __shared__ float dus[LL];
    __shared__ float us[LL];
    __shared__ float zs[LL];
    __shared__ float ApL[DS][9];
    __shared__ float HlL[DS][9];
    __shared__ float hst[DS][9];

    {
        const int t = tid;
        const size_t row = (size_t)b * LL + t;
        const float* xd = xdbl + row * XROW;
        const float* w = dtw + d * DTR;
        float acc = dtb[d];
#pragma unroll
        for (int k = 0; k < DTR; k++) acc += xd[k] * w[k];
        float delta = fmaxf(acc, 0.f) + log1pf(__expf(-fabsf(acc)));  // softplus
        float u = bf2f((short)xcbf[row * DI + d]);
        dus[t] = delta * u;
        us[t] = u;
        zs[t] = bf2f((short)zsbf[row * DI + d]);
#pragma unroll
        for (int s = 0; s < DS; s++) {
            da[t][s] = __expf(delta * (-__expf(Alog[d * DS + s])));
            Bsh[t][s] = xd[DTR + s];
            Csh[t][s] = xd[DTR + DS + s];
        }
    }
    __syncthreads();

    const int s = tid & 15;
    const int c = tid >> 4;           // chunk 0..7

    {
        float h = 0.f, Ap = 1.f;
#pragma unroll
        for (int q = 0; q < 16; q++) {
            int t = c * 16 + q;
            float a = da[t][s];
            h = h * a + dus[t] * Bsh[t][s];
            Ap *= a;
        }
        ApL[s][c] = Ap;
        HlL[s][c] = h;
    }
    __syncthreads();
    if (tid < DS) {
        float hs = 0.f;
#pragma unroll
        for (int cc = 0; cc < 8; cc++) {
            hst[tid][cc] = hs;
            hs = ApL[tid][cc] * hs + HlL[tid][cc];
        }
    }
    __syncthreads();

    {
        const float Dd = Dp[d];
        float h = hst[s][c];
        unsigned short* yc = ybf + ((size_t)b * LL + c * 16) * DI + d;
#pragma unroll
        for (int q = 0; q < 16; q++) {
            int t = c * 16 + q;
            float a = da[t][s];
            h = h * a + dus[t] * Bsh[t][s];
            float p = h * Csh[t][s];
            p += __shfl_xor(p, 1, 16);
            p += __shfl_xor(p, 2, 16);
            p += __shfl_xor(p, 4, 16);
            p += __shfl_xor(p, 8, 16);
            if (s == 0) yc[(size_t)q * DI] = f2bf((p + Dd * us[t]) * zs[t]);
        }
    }
}

// ---------------------------------------------------------------- out-proj MFMA GEMM, direct residual RMW on t.
// grid (6, 32): x = 64-col tile, y = 32-row tile.  K = 768.  Each t element touched once.
__global__ __launch_bounds__(256) void k_mfma_op(
    const unsigned short* __restrict__ ybf,
    const unsigned short* __restrict__ owbf,
    float* __restrict__ t)
{
    const int tid = threadIdx.x;
    const int wave = tid >> 6, lane = tid & 63;
    const int quad = lane >> 4, r = lane & 15;
    const int wr2 = wave >> 1, wc = wave & 1;
    const int n0 = blockIdx.x * 64 + wc * 32;
    const int m0 = blockIdx.y * 32 + wr2 * 16;

    floatx4 acc[2] = {};
    const unsigned short* Ab = ybf + (size_t)(m0 + r) * DI + quad * 8;
    const unsigned short* Bb = owbf + (size_t)(n0 + r) * DI + quad * 8;
    for (int k0 = 0; k0 < DI; k0 += 32) {
        bf16x8 af = *(const bf16x8*)(Ab + k0);
        bf16x8 b0 = *(const bf16x8*)(Bb + k0);
        bf16x8 b1 = *(const bf16x8*)(Bb + (size_t)16 * DI + k0);
        acc[0] = __builtin_amdgcn_mfma_f32_16x16x32_bf16(af, b0, acc[0], 0, 0, 0);
        acc[1] = __builtin_amdgcn_mfma_f32_16x16x32_bf16(af, b1, acc[1], 0, 0, 0);
    }

#pragma unroll
    for (int j = 0; j < 2; j++) {
        int col = n0 + j * 16 + r;
#pragma unroll
        for (int r2 = 0; r2 < 4; r2++) {
            int row = m0 + quad * 4 + r2;
            float* tp = t + (size_t)row * DD + col;
            *tp += acc[j][r2];
        }
    }
}

// ---------------------------------------------------------------- final LN + partial mean-pool: grid (8 chunks, 8 batches)
__global__ __launch_bounds__(256) void k_lnpool(const float* __restrict__ t,
                                                const float* __restrict__ ng,
                                                const float* __restrict__ nb,
                                                float* __restrict__ pparts)  // [BB][8][DD]
{
    const int b = blockIdx.y, chunk = blockIdx.x;
    const int tid = threadIdx.x;
    const int wave = tid >> 6, lane = tid & 63;
    __shared__ float pw[4][DD];

    for (int c = lane; c < DD; c += 64) pw[wave][c] = 0.f;
    __syncthreads();

    for (int rr = 0; rr < 4; rr++) {
        const int row = b * LL + chunk * 16 + wave * 4 + rr;
        const float* xr = t + (size_t)row * DD;
        float v[6];
        float s = 0.f, q = 0.f;
#pragma unroll
        for (int j = 0; j < 6; j++) { v[j] = xr[lane + 64 * j]; s += v[j]; q += v[j] * v[j]; }
#pragma unroll
        for (int off = 32; off; off >>= 1) { s += __shfl_xor(s, off); q += __shfl_xor(q, off); }
        float mean = s * (1.0f / DD);
        float var = q * (1.0f / DD) - mean * mean;
        float inv = 1.0f / sqrtf(var + 1e-5f);
#pragma unroll
        for (int j = 0; j < 6; j++) {
            int c = lane + 64 * j;
            pw[wave][c] += (v[j] - mean) * inv * ng[c] + nb[c];
        }
    }
    __syncthreads();
    float* out = pparts + ((size_t)b * 8 + chunk) * DD;
    for (int c = tid; c < DD; c += 256)
        out[c] = pw[0][c] + pw[1][c] + pw[2][c] + pw[3][c];
}

// ---------------------------------------------------------------- head MLP from pooled partials, one block per batch
__global__ __launch_bounds__(256) void k_mlp(const float* __restrict__ pparts,
    const float* __restrict__ w1, const float* __restrict__ b1,
    const float* __restrict__ w2, const float* __restrict__ b2,
    const float* __restrict__ w3, const float* __restrict__ b3,
    float* __restrict__ out)
{
    const int b = blockIdx.x, tid = threadIdx.x;
    __shared__ float pl[DD];
    __shared__ float h1[256];
    __shared__ float h2[64];
    for (int c = tid; c < DD; c += 256) {
        const float* pp = pparts + (size_t)b * 8 * DD + c;
        float s = 0.f;
#pragma unroll
        for (int z = 0; z < 8; z++) s += pp[z * DD];
        pl[c] = s * (1.0f / LL);
    }
    __syncthreads();

    {
        float acc = b1[tid];
        const float* wr = w1 + (size_t)tid * DD;
        for (int k = 0; k < DD; k++) acc += pl[k] * wr[k];
        h1[tid] = fmaxf(acc, 0.f);
    }
    __syncthreads();
    if (tid < 64) {
        float acc = b2[tid];
        const float* wr = w2 + (size_t)tid * 256;
        for (int k = 0; k < 256; k++) acc += h1[k] * wr[k];
        h2[tid] = fmaxf(acc, 0.f);
    }
    __syncthreads();
    if (tid < NC) {
        float acc = b3[tid];
        const float* wr = w3 + (size_t)tid * 64;
        for (int k = 0; k < 64; k++) acc += h2[k] * wr[k];
        out[b * NC + tid] = acc;
    }
}

// ---------------------------------------------------------------- launch
extern "C" void kernel_launch(void* const* d_in, const int* in_sizes, int n_in,
                              void* d_out, int out_size, void* d_ws, size_t ws_size,
                              hipStream_t stream)
{
    const float* data      = (const float*)d_in[0];
    const float* pe_w1     = (const float*)d_in[1];
    const float* pe_b1     = (const float*)d_in[2];
    const float* pe_g1     = (const float*)d_in[3];
    const float* pe_be1    = (const float*)d_in[4];
    const float* pe_w2     = (const float*)d_in[5];
    const float* pe_b2     = (const float*)d_in[6];
    const float* pe_g2     = (const float*)d_in[7];
    const float* pe_be2    = (const float*)d_in[8];
    const float* pe_w3     = (const float*)d_in[9];
    const float* pe_b3     = (const float*)d_in[10];
    const float* pe_g3     = (const float*)d_in[11];
    const float* pe_be3    = (const float*)d_in[12];
    const float* oi_h_scale  = (const float*)d_in[13];
    const float* oi_h_shift  = (const float*)d_in[14];
    const float* oi_th_scale = (const float*)d_in[15];
    const float* oi_th_shift = (const float*)d_in[16];
    const float* pos_embed = (const float*)d_in[17];
    const float* blk_ln_g  = (const float*)d_in[18];
    const float* blk_ln_b  = (const float*)d_in[19];
    const float* blk_in_w  = (const float*)d_in[20];
    const float* blk_conv_w = (const float*)d_in[21];
    const float* blk_conv_b = (const float*)d_in[22];
    const float* blk_xp_w  = (const float*)d_in[23];
    const float* blk_dt_w  = (const float*)d_in[24];
    const float* blk_dt_b  = (const float*)d_in[25];
    const float* blk_Alog  = (const float*)d_in[26];
    const float* blk_D     = (const float*)d_in[27];
    const float* blk_out_w = (const float*)d_in[28];
    const float* norm_g    = (const float*)d_in[29];
    const float* norm_b    = (const float*)d_in[30];
    const float* mlp_w1    = (const float*)d_in[31];
    const float* mlp_b1    = (const float*)d_in[32];
    const float* mlp_w2    = (const float*)d_in[33];
    const float* mlp_b2    = (const float*)d_in[34];
    const float* mlp_w3    = (const float*)d_in[35];
    const float* mlp_b3    = (const float*)d_in[36];

    float* ws = (float*)d_ws;
    size_t off = 0;
    auto alloc = [&](size_t n) { float* p = ws + off; off += (n + 63) & ~(size_t)63; return p; };
    float* tokens  = alloc((size_t)BB * PP * DD);
    float* centers = alloc((size_t)BB * PP * 3);
    int*   knn_idx = (int*)alloc((size_t)BB * PP * KK);
    float* t    = alloc((size_t)NR * DD);
    float* xdbl = alloc((size_t)NR * XROW);
    float* pparts  = alloc((size_t)BB * 8 * DD);
    unsigned short* tbf   = (unsigned short*)alloc((size_t)NR * DD / 2);
    unsigned short* xcbf  = (unsigned short*)alloc((size_t)NR * DI / 2);
    unsigned short* zsbf  = (unsigned short*)alloc((size_t)NR * DI / 2);
    unsigned short* ybf   = (unsigned short*)alloc((size_t)NR * DI / 2);
    unsigned short* inwbf = (unsigned short*)alloc((size_t)DEPTH * 2 * DI * DD / 2);
    unsigned short* owbf  = (unsigned short*)alloc((size_t)DEPTH * DD * DI / 2);
    unsigned short* xpbf  = (unsigned short*)alloc((size_t)DEPTH * 64 * DI / 2);
    unsigned short* w3bf  = (unsigned short*)alloc((size_t)DD * 128 / 2);

    // one-shot weight conversion (all four targets in one kernel)
    {
        const int total = DEPTH * 2 * DI * DD + DEPTH * DD * DI + DD * 128 + DEPTH * 64 * DI;
        k_cvt<<<(total + 255) / 256, 256, 0, stream>>>(
            blk_in_w, blk_out_w, pe_w3, blk_xp_w, inwbf, owbf, w3bf, xpbf);
    }

    k_knn<<<BB * PP, 256, 0, stream>>>(data, knn_idx, centers);
    k_pe_mlp<<<BB * PP, 256, 0, stream>>>(data, knn_idx,
        pe_w1, pe_b1, pe_g1, pe_be1, pe_w2, pe_b2, pe_g2, pe_be2,
        w3bf, pe_b3, pe_g3, pe_be3, tokens);
    k_build_t<<<dim3(16, BB), 256, 0, stream>>>(tokens, centers,
        oi_h_scale, oi_h_shift, oi_th_scale, oi_th_shift, pos_embed, t);

    for (int i = 0; i < DEPTH; i++) {
        const float* ln_g = blk_ln_g + i * DD;
        const float* ln_b = blk_ln_b + i * DD;
        const float* cw   = blk_conv_w + (size_t)i * DI * DCONV;
        const float* cb   = blk_conv_b + (size_t)i * DI;
        const float* dtw  = blk_dt_w + (size_t)i * DI * DTR;
        const float* dtb  = blk_dt_b + (size_t)i * DI;
        const float* Al   = blk_Alog + (size_t)i * DI * DS;
        const float* Dpp  = blk_D + (size_t)i * DI;
        const unsigned short* inw = inwbf + (size_t)i * 2 * DI * DD;
        const unsigned short* ow  = owbf + (size_t)i * DD * DI;
        const unsigned short* xpb = xpbf + (size_t)i * 64 * DI;

        k_stats<<<NR / 4, 256, 0, stream>>>(t, ln_g, ln_b, tbf, xdbl);
        k_mfma_xz<<<dim3(24, BB), 256, 0, stream>>>(
            tbf, inw, cw, cb, xpb, xcbf, zsbf, xdbl);
        k_scan<<<BB * DI, 128, 0, stream>>>(xdbl, xcbf, zsbf, dtw, dtb, Al, Dpp, ybf);
        k_mfma_op<<<dim3(DD / 64, NR / 32), 256, 0, stream>>>(ybf, ow, t);
    }

    k_lnpool<<<dim3(8, BB), 256, 0, stream>>>(t, norm_g, norm_b, pparts);
    k_mlp<<<BB, 256, 0, stream>>>(pparts, mlp_w1, mlp_b1, mlp_w2, mlp_b2, mlp_w3, mlp_b3,
                                  (float*)d_out);
}